// Round 3
// baseline (101.825 us; speedup 1.0000x reference)
//
#include <hip/hip_runtime.h>

#define THRESH 0.95f
#define MAXL 64

// Kernel A v3: one block per batch. 64 threads stage alphas[b,:] into LDS,
// then thread 0 runs the bit-exact serial integrate-and-fire chain:
//   i = integ + a; fire = i > 0.95; integ = fire ? i - 1 : i    (branchless)
// Fire recording is hoisted to ONE rare branch per 4 steps (OR of 4 flags),
// keeping the per-step critical path at add -> {cmp,sub} -> cndmask.
// 3-deep float4 prefetch from LDS hides ds_read latency (~120cy < 3*48cy).
__global__ __launch_bounds__(64) void cif_scan(
    const float* __restrict__ alphas, int T, int B,
    int* __restrict__ nf, int* __restrict__ fireT,
    float* __restrict__ curAt, float* __restrict__ remAt) {
    __shared__ __align__(16) float sa[2048];
    int b = blockIdx.x;
    const float* arow = alphas + (size_t)b * T;

    int tid = threadIdx.x;
    int T4 = T >> 2;
    if ((((uintptr_t)arow) & 15) == 0) {
        const float4* g4 = (const float4*)arow;
        float4* s4w = (float4*)sa;
        for (int i = tid; i < T4; i += 64) s4w[i] = g4[i];
        for (int i = T4 * 4 + tid; i < T; i += 64) sa[i] = arow[i];
    } else {
        for (int i = tid; i < T; i += 64) sa[i] = arow[i];
    }
    __syncthreads();

    if (tid != 0) return;

    float integ = 0.0f;
    int n = 0;
    int* fT = fireT + b * MAXL;
    float* cA = curAt + b * MAXL;
    float* rA = remAt + b * MAXL;

    const float4* s4 = (const float4*)sa;
    int ng = T >> 2;

    float4 f0, f1, f2;
    if (ng > 0) f0 = s4[0];
    if (ng > 1) f1 = s4[1];
    if (ng > 2) f2 = s4[2];

    for (int g = 0; g < ng; ++g) {
        float4 cf = f0;
        f0 = f1; f1 = f2;
        if (g + 3 < ng) f2 = s4[g + 3];

        float p0 = integ;
        float i0 = p0 + cf.x; bool q0 = i0 > THRESH; float j0 = q0 ? i0 - 1.0f : i0;
        float i1 = j0 + cf.y; bool q1 = i1 > THRESH; float j1 = q1 ? i1 - 1.0f : i1;
        float i2 = j1 + cf.z; bool q2 = i2 > THRESH; float j2 = q2 ? i2 - 1.0f : i2;
        float i3 = j2 + cf.w; bool q3 = i3 > THRESH; float j3 = q3 ? i3 - 1.0f : i3;

        if (q0 | q1 | q2 | q3) {   // rare (~12% of groups)
            int tb = g << 2;
            if (q0) { if (n < MAXL) { float dc = 1.0f - p0; fT[n] = tb;     cA[n] = dc; rA[n] = cf.x - dc; } ++n; }
            if (q1) { if (n < MAXL) { float dc = 1.0f - j0; fT[n] = tb + 1; cA[n] = dc; rA[n] = cf.y - dc; } ++n; }
            if (q2) { if (n < MAXL) { float dc = 1.0f - j1; fT[n] = tb + 2; cA[n] = dc; rA[n] = cf.z - dc; } ++n; }
            if (q3) { if (n < MAXL) { float dc = 1.0f - j2; fT[n] = tb + 3; cA[n] = dc; rA[n] = cf.w - dc; } ++n; }
        }
        integ = j3;
    }
    // scalar tail (T % 4)
    for (int t = ng << 2; t < T; ++t) {
        float a = sa[t];
        float p = integ;
        float i = p + a; bool q = i > THRESH;
        if (q) {
            if (n < MAXL) { float dc = 1.0f - p; fT[n] = t; cA[n] = dc; rA[n] = a - dc; }
            ++n;
            integ = i - 1.0f;
        } else {
            integ = i;
        }
    }
    nf[b] = (n < MAXL) ? n : MAXL;
}

// Kernel B v3: one block per (batch, label), float4 over H.
// out[b,k,:] = rem[k-1]*h[tp] + sum_{t in (tp, tf)} a_t*h[t] + cur[k]*h[tf]
// accumulated in ascending t; per-element accumulation order matches the
// reference scan. Labels k >= fire count write zeros (d_out is poisoned).
__global__ __launch_bounds__(128) void cif_gather(
    const float* __restrict__ hidden, const float* __restrict__ alphas,
    int T, int H,
    const int* __restrict__ nf, const int* __restrict__ fireT,
    const float* __restrict__ curAt, const float* __restrict__ remAt,
    float* __restrict__ out) {
    int b = blockIdx.x >> 6;
    int k = blockIdx.x & (MAXL - 1);

    int valid = (k < nf[b]);
    int tf = 0, t0 = 0, tp = 0;
    float rw = 0.0f, cw = 0.0f;
    if (valid) {
        tf = fireT[b * MAXL + k];
        cw = curAt[b * MAXL + k];
        if (k > 0) {
            tp = fireT[b * MAXL + k - 1];
            rw = remAt[b * MAXL + k - 1];
            t0 = tp + 1;
        }
    }

    const float* arow = alphas + (size_t)b * T;

    if ((H & 3) == 0) {
        int W = H >> 2;
        const float4* hb4 = (const float4*)(hidden + (size_t)b * T * H);
        float4* out4 = (float4*)(out + (size_t)blockIdx.x * H);
        for (int h4 = threadIdx.x; h4 < W; h4 += blockDim.x) {
            float4 acc = make_float4(0.f, 0.f, 0.f, 0.f);
            if (valid) {
                if (k > 0) {
                    float4 m = hb4[(size_t)tp * W + h4];
                    acc.x = rw * m.x; acc.y = rw * m.y;
                    acc.z = rw * m.z; acc.w = rw * m.w;
                }
                for (int t = t0; t < tf; ++t) {
                    float4 m = hb4[(size_t)t * W + h4];
                    float a = arow[t];
                    acc.x += a * m.x; acc.y += a * m.y;
                    acc.z += a * m.z; acc.w += a * m.w;
                }
                float4 m = hb4[(size_t)tf * W + h4];
                acc.x += cw * m.x; acc.y += cw * m.y;
                acc.z += cw * m.z; acc.w += cw * m.w;
            }
            out4[h4] = acc;
        }
    } else {
        const float* hb = hidden + (size_t)b * T * H;
        size_t obase = (size_t)blockIdx.x * H;
        for (int h = threadIdx.x; h < H; h += blockDim.x) {
            float acc = 0.0f;
            if (valid) {
                if (k > 0) acc = rw * hb[(size_t)tp * H + h];
                for (int t = t0; t < tf; ++t)
                    acc += arow[t] * hb[(size_t)t * H + h];
                acc += cw * hb[(size_t)tf * H + h];
            }
            out[obase + h] = acc;
        }
    }
}

extern "C" void kernel_launch(void* const* d_in, const int* in_sizes, int n_in,
                              void* d_out, int out_size, void* d_ws, size_t ws_size,
                              hipStream_t stream) {
    const float* hidden = (const float*)d_in[0];
    const float* alphas = (const float*)d_in[1];
    float* out = (float*)d_out;

    long BT  = in_sizes[1];          // B*T
    long BTH = in_sizes[0];          // B*T*H
    int H = (int)(BTH / BT);         // 512
    int B = (int)((long)out_size / ((long)MAXL * H)); // 32
    int T = (int)(BT / B);           // 2000

    char* ws = (char*)d_ws;
    int*   nf    = (int*)ws;                              // B ints
    int*   fireT = (int*)(ws + 256);                      // B*MAXL ints
    float* curAt = (float*)(ws + 256 + (size_t)B * MAXL * 4);
    float* remAt = (float*)(ws + 256 + 2 * (size_t)B * MAXL * 4);

    cif_scan<<<B, 64, 0, stream>>>(alphas, T, B, nf, fireT, curAt, remAt);
    cif_gather<<<B * MAXL, 128, 0, stream>>>(hidden, alphas, T, H, nf, fireT, curAt, remAt, out);
}

// Round 4
// 60.088 us; speedup vs baseline: 1.6946x; 1.6946x over previous
//
#include <hip/hip_runtime.h>

#define THRESH 0.95f
#define MAXL 64
#define WIN 8

// Kernel A v4: one block per batch. 64 threads stage alphas[b,:] into LDS,
// then thread 0 runs a SPECULATIVE window scan:
//   - 8 straight dependent adds (bit-exact prefix of the reference chain up
//     to the first fire in the window)
//   - max-tree over the 8 partials; if max <= 0.95 no step fired and every
//     partial equals the reference value -> integ = s7, done (74% of windows)
//   - else exact per-step rescan (add -> cmp -> maybe record+sub-1), which
//     replays the reference arithmetic exactly including resets.
// LDS prefetch: 4 static (float4,float4) window buffers, loop unrolled x4 so
// the ds_read lands 3 windows (~126 cyc) before use. No register rotation.
__global__ __launch_bounds__(64) void cif_scan(
    const float* __restrict__ alphas, int T, int B,
    int* __restrict__ nf, int* __restrict__ fireT,
    float* __restrict__ curAt, float* __restrict__ remAt) {
    __shared__ __align__(16) float sa[2080];   // assumes T <= 2048 (T=2000); pad for prefetch overrun
    int b = blockIdx.x;
    const float* arow = alphas + (size_t)b * T;

    int tid = threadIdx.x;
    int T4 = T >> 2;
    if ((((uintptr_t)arow) & 15) == 0) {
        const float4* g4 = (const float4*)arow;
        float4* s4w = (float4*)sa;
        for (int i = tid; i < T4; i += 64) s4w[i] = g4[i];
        for (int i = T4 * 4 + tid; i < T; i += 64) sa[i] = arow[i];
    } else {
        for (int i = tid; i < T; i += 64) sa[i] = arow[i];
    }
    __syncthreads();

    if (tid != 0) return;

    int* fT = fireT + b * MAXL;
    float* cA = curAt + b * MAXL;
    float* rA = remAt + b * MAXL;

    float integ = 0.0f;
    int n = 0;

    const float4* sp4 = (const float4*)sa;
    int nw = T / WIN;

    // 4 static window buffers (a = lo float4, b = hi float4)
    float4 b0a, b0b, b1a, b1b, b2a, b2b, b3a, b3b;
    b0a = sp4[0]; b0b = sp4[1];
    b1a = sp4[2]; b1b = sp4[3];
    b2a = sp4[4]; b2b = sp4[5];

// window body: consume Xa/Xb (window WIDX), prefetch window LIDX into Ya/Yb.
// Prefetch reads past nw are safe: sa has 2080 floats (520 float4s) and
// LIDX <= nw+2 -> float4 index <= 2*nw+5 <= 505 for T=2000.
#define DOWIN(Xa, Xb, Ya, Yb, WIDX, LIDX)                                    \
    {                                                                        \
        float c0 = Xa.x, c1 = Xa.y, c2 = Xa.z, c3 = Xa.w;                    \
        float c4 = Xb.x, c5 = Xb.y, c6 = Xb.z, c7 = Xb.w;                    \
        Ya = sp4[(LIDX) * 2];                                                \
        Yb = sp4[(LIDX) * 2 + 1];                                            \
        float s0 = integ + c0;                                               \
        float s1 = s0 + c1;                                                  \
        float s2 = s1 + c2;                                                  \
        float s3 = s2 + c3;                                                  \
        float s4_ = s3 + c4;                                                 \
        float s5 = s4_ + c5;                                                 \
        float s6 = s5 + c6;                                                  \
        float s7 = s6 + c7;                                                  \
        float m01 = fmaxf(s0, s1), m23 = fmaxf(s2, s3);                      \
        float m45 = fmaxf(s4_, s5), m67 = fmaxf(s6, s7);                     \
        float mx = fmaxf(fmaxf(m01, m23), fmaxf(m45, m67));                  \
        if (__builtin_expect(mx > THRESH, 0)) {                              \
            float vv[8] = {c0, c1, c2, c3, c4, c5, c6, c7};                  \
            float cur = integ;                                               \
            _Pragma("unroll")                                                \
            for (int ii = 0; ii < 8; ++ii) {                                 \
                float p = cur;                                               \
                float iv = p + vv[ii];                                       \
                if (iv > THRESH) {                                           \
                    if (n < MAXL) {                                          \
                        float dc = 1.0f - p;                                 \
                        fT[n] = (WIDX) * WIN + ii;                           \
                        cA[n] = dc;                                          \
                        rA[n] = vv[ii] - dc;                                 \
                    }                                                        \
                    ++n;                                                     \
                    iv = iv - 1.0f;                                          \
                }                                                            \
                cur = iv;                                                    \
            }                                                                \
            integ = cur;                                                     \
        } else {                                                             \
            integ = s7;                                                      \
        }                                                                    \
    }

    int w = 0;
    for (; w + 4 <= nw; w += 4) {
        DOWIN(b0a, b0b, b3a, b3b, w,     w + 3);
        DOWIN(b1a, b1b, b0a, b0b, w + 1, w + 4);
        DOWIN(b2a, b2b, b1a, b1b, w + 2, w + 5);
        DOWIN(b3a, b3b, b2a, b2b, w + 3, w + 6);
    }
#undef DOWIN
    // leftover windows + tail steps: exact scalar path straight from LDS
    for (int t = w * WIN; t < T; ++t) {
        float a = sa[t];
        float p = integ;
        float iv = p + a;
        if (iv > THRESH) {
            if (n < MAXL) {
                float dc = 1.0f - p;
                fT[n] = t; cA[n] = dc; rA[n] = a - dc;
            }
            ++n;
            iv = iv - 1.0f;
        }
        integ = iv;
    }
    nf[b] = (n < MAXL) ? n : MAXL;
}

// Kernel B (unchanged, at HBM roofline): one block per (batch, label), float4
// over H. out[b,k,:] = rem[k-1]*h[tp] + sum_{t in (tp,tf)} a_t*h[t] + cur*h[tf]
// accumulated in ascending t (matches reference rounding; absmax was 0.0).
// Labels k >= fire count write zeros (d_out is poisoned by the harness).
__global__ __launch_bounds__(128) void cif_gather(
    const float* __restrict__ hidden, const float* __restrict__ alphas,
    int T, int H,
    const int* __restrict__ nf, const int* __restrict__ fireT,
    const float* __restrict__ curAt, const float* __restrict__ remAt,
    float* __restrict__ out) {
    int b = blockIdx.x >> 6;
    int k = blockIdx.x & (MAXL - 1);

    int valid = (k < nf[b]);
    int tf = 0, t0 = 0, tp = 0;
    float rw = 0.0f, cw = 0.0f;
    if (valid) {
        tf = fireT[b * MAXL + k];
        cw = curAt[b * MAXL + k];
        if (k > 0) {
            tp = fireT[b * MAXL + k - 1];
            rw = remAt[b * MAXL + k - 1];
            t0 = tp + 1;
        }
    }

    const float* arow = alphas + (size_t)b * T;

    if ((H & 3) == 0) {
        int W = H >> 2;
        const float4* hb4 = (const float4*)(hidden + (size_t)b * T * H);
        float4* out4 = (float4*)(out + (size_t)blockIdx.x * H);
        for (int h4 = threadIdx.x; h4 < W; h4 += blockDim.x) {
            float4 acc = make_float4(0.f, 0.f, 0.f, 0.f);
            if (valid) {
                if (k > 0) {
                    float4 m = hb4[(size_t)tp * W + h4];
                    acc.x = rw * m.x; acc.y = rw * m.y;
                    acc.z = rw * m.z; acc.w = rw * m.w;
                }
                for (int t = t0; t < tf; ++t) {
                    float4 m = hb4[(size_t)t * W + h4];
                    float a = arow[t];
                    acc.x += a * m.x; acc.y += a * m.y;
                    acc.z += a * m.z; acc.w += a * m.w;
                }
                float4 m = hb4[(size_t)tf * W + h4];
                acc.x += cw * m.x; acc.y += cw * m.y;
                acc.z += cw * m.z; acc.w += cw * m.w;
            }
            out4[h4] = acc;
        }
    } else {
        const float* hb = hidden + (size_t)b * T * H;
        size_t obase = (size_t)blockIdx.x * H;
        for (int h = threadIdx.x; h < H; h += blockDim.x) {
            float acc = 0.0f;
            if (valid) {
                if (k > 0) acc = rw * hb[(size_t)tp * H + h];
                for (int t = t0; t < tf; ++t)
                    acc += arow[t] * hb[(size_t)t * H + h];
                acc += cw * hb[(size_t)tf * H + h];
            }
            out[obase + h] = acc;
        }
    }
}

extern "C" void kernel_launch(void* const* d_in, const int* in_sizes, int n_in,
                              void* d_out, int out_size, void* d_ws, size_t ws_size,
                              hipStream_t stream) {
    const float* hidden = (const float*)d_in[0];
    const float* alphas = (const float*)d_in[1];
    float* out = (float*)d_out;

    long BT  = in_sizes[1];          // B*T
    long BTH = in_sizes[0];          // B*T*H
    int H = (int)(BTH / BT);         // 512
    int B = (int)((long)out_size / ((long)MAXL * H)); // 32
    int T = (int)(BT / B);           // 2000

    char* ws = (char*)d_ws;
    int*   nf    = (int*)ws;                              // B ints
    int*   fireT = (int*)(ws + 256);                      // B*MAXL ints
    float* curAt = (float*)(ws + 256 + (size_t)B * MAXL * 4);
    float* remAt = (float*)(ws + 256 + 2 * (size_t)B * MAXL * 4);

    cif_scan<<<B, 64, 0, stream>>>(alphas, T, B, nf, fireT, curAt, remAt);
    cif_gather<<<B * MAXL, 128, 0, stream>>>(hidden, alphas, T, H, nf, fireT, curAt, remAt, out);
}